// Round 15
// baseline (544.027 us; speedup 1.0000x reference)
//
#include <hip/hip_runtime.h>
#include <hip/hip_bf16.h>
#include <stdint.h>

#define Hn   1024
#define NHn  16
#define DHn  64
#define Ln   2
#define En   8
#define Fn   4096
#define Bn   2
#define Sn   1024
#define Tn   2048   // B*S
#define An   4096   // assignments = Tn*2
#define KSPLIT 4

typedef __bf16 bf16_t;
typedef __bf16 bf16x2 __attribute__((ext_vector_type(2)));
typedef __bf16 bf16x4 __attribute__((ext_vector_type(4)));
typedef __bf16 bf16x8 __attribute__((ext_vector_type(8)));
typedef float  f32x4  __attribute__((ext_vector_type(4)));

__device__ __forceinline__ f32x4 mfma16(bf16x8 a, bf16x8 b, f32x4 c){
  return __builtin_amdgcn_mfma_f32_16x16x32_bf16(a, b, c, 0, 0, 0);
}
__device__ __forceinline__ void gload16(const void* gsrc, void* ldst){
  __builtin_amdgcn_global_load_lds((const __attribute__((address_space(1))) void*)gsrc,
                                   (__attribute__((address_space(3))) void*)ldst, 16, 0, 0);
}
__device__ __forceinline__ float gelu_f(float x){
  float u = 0.7978845608028654f * (x + 0.044715f * x * x * x);
  return 0.5f * x * (1.0f + tanhf(u));
}

// ---------- transpose + fp32->bf16 (vectorized): dst[c][r] = (bf16)src[r][c] ----------
__global__ __launch_bounds__(256)
void tcvt_k(const float* __restrict__ src, bf16_t* __restrict__ dst, int R, int C){
  __shared__ float tile[64][68];
  size_t moff = (size_t)blockIdx.z * R * C;
  src += moff; dst += moff;
  int c0 = blockIdx.x * 64, r0 = blockIdx.y * 64;
  int tid = threadIdx.x;
  int tx = tid & 15, ty = tid >> 4;
  #pragma unroll
  for (int i = 0; i < 4; ++i){
    float4 v = *(const float4*)(src + (size_t)(r0 + ty + i*16) * C + c0 + tx*4);
    *(float4*)&tile[ty + i*16][tx*4] = v;
  }
  __syncthreads();
  int c = tid >> 2, rq = tid & 3;
  #pragma unroll
  for (int i = 0; i < 2; ++i){
    int rr = (rq + i*4) * 8;
    bf16x8 pk;
    #pragma unroll
    for (int j = 0; j < 8; ++j) pk[j] = (bf16_t)tile[rr + j][c];
    *(bf16x8*)(dst + (size_t)(c0 + c) * R + r0 + rr) = pk;
  }
}

// ---------- LayerNorm (LN1): one block per row ----------
__global__ __launch_bounds__(256)
void ln_k(const float* __restrict__ x, const float* __restrict__ gam,
          const float* __restrict__ bet, bf16_t* __restrict__ out){
  int row = blockIdx.x;
  const float4* xr = (const float4*)(x + (size_t)row * Hn);
  int t = threadIdx.x, lane = t & 63, w = t >> 6;
  float4 v = xr[t];
  float s  = v.x + v.y + v.z + v.w;
  float ss = v.x*v.x + v.y*v.y + v.z*v.z + v.w*v.w;
  #pragma unroll
  for (int mk = 1; mk < 64; mk <<= 1){ s += __shfl_xor(s, mk); ss += __shfl_xor(ss, mk); }
  __shared__ float r1[4], r2[4];
  if (lane == 0){ r1[w] = s; r2[w] = ss; }
  __syncthreads();
  float S1 = r1[0]+r1[1]+r1[2]+r1[3];
  float S2 = r2[0]+r2[1]+r2[2]+r2[3];
  float mean = S1 * (1.0f/Hn);
  float var  = S2 * (1.0f/Hn) - mean*mean;
  float rstd = rsqrtf(var + 1e-5f);
  int c = t * 4;
  bf16_t* o = out + (size_t)row * Hn + c;
  o[0] = (bf16_t)((v.x-mean)*rstd*gam[c+0] + bet[c+0]);
  o[1] = (bf16_t)((v.y-mean)*rstd*gam[c+1] + bet[c+1]);
  o[2] = (bf16_t)((v.z-mean)*rstd*gam[c+2] + bet[c+2]);
  o[3] = (bf16_t)((v.w-mean)*rstd*gam[c+3] + bet[c+3]);
}

// ---------- fused: x2 = x + w0*o0 + w1*o1 ; xn2 = bf16(LN2(x2)) ----------
__global__ __launch_bounds__(256)
void res_ln2_k(const float* __restrict__ x, const float* __restrict__ o0,
               const float* __restrict__ o1, const float* __restrict__ lvl,
               const float* __restrict__ gam, const float* __restrict__ bet,
               float* __restrict__ x2, bf16_t* __restrict__ xn2){
  int row = blockIdx.x, t = threadIdx.x, lane = t & 63, w = t >> 6;
  float l0 = lvl[0], l1 = lvl[1];
  float mx = fmaxf(l0, l1);
  float e0 = __expf(l0 - mx), e1 = __expf(l1 - mx);
  float inv = 1.f / (e0 + e1);
  float w0 = e0 * inv, w1 = e1 * inv;
  size_t base = (size_t)row * Hn;
  float4 xv = ((const float4*)(x  + base))[t];
  float4 a0 = ((const float4*)(o0 + base))[t];
  float4 a1 = ((const float4*)(o1 + base))[t];
  float4 v;
  v.x = xv.x + w0*a0.x + w1*a1.x;
  v.y = xv.y + w0*a0.y + w1*a1.y;
  v.z = xv.z + w0*a0.z + w1*a1.z;
  v.w = xv.w + w0*a0.w + w1*a1.w;
  ((float4*)(x2 + base))[t] = v;
  float s  = v.x + v.y + v.z + v.w;
  float ss = v.x*v.x + v.y*v.y + v.z*v.z + v.w*v.w;
  #pragma unroll
  for (int mk = 1; mk < 64; mk <<= 1){ s += __shfl_xor(s, mk); ss += __shfl_xor(ss, mk); }
  __shared__ float r1[4], r2[4];
  if (lane == 0){ r1[w] = s; r2[w] = ss; }
  __syncthreads();
  float S1 = r1[0]+r1[1]+r1[2]+r1[3];
  float S2 = r2[0]+r2[1]+r2[2]+r2[3];
  float mean = S1 * (1.0f/Hn);
  float var  = S2 * (1.0f/Hn) - mean*mean;
  float rstd = rsqrtf(var + 1e-5f);
  int c = t * 4;
  bf16_t* o = xn2 + base + c;
  o[0] = (bf16_t)((v.x-mean)*rstd*gam[c+0] + bet[c+0]);
  o[1] = (bf16_t)((v.y-mean)*rstd*gam[c+1] + bet[c+1]);
  o[2] = (bf16_t)((v.z-mean)*rstd*gam[c+2] + bet[c+2]);
  o[3] = (bf16_t)((v.w-mean)*rstd*gam[c+3] + bet[c+3]);
}

// ---------- dense GEMM: 128x128 tile, BK=32, 2-phase dbuf prefetch (unchanged control) ----------
// MODE 0: QKV proj, z in [0,6): z<4 -> q/k [z][hh][s][d]; z>=4 -> V^T [z][hh][d][s]
// MODE 1: O-proj,   z=l in [0,2): out fp32 otmp[l] = acc + bias
struct GP {
  const bf16_t* A;
  const bf16_t* Bt;
  const float*  bias;
  float*        fout;
  bf16_t*       bfout;
  const int*    list;
  const int*    counts;
  int Kstride;
  int Kloc;
};

template<int MODE>
__global__ __launch_bounds__(256)
void gemm_k(GP p){
  const int nt = blockIdx.x, mt = blockIdx.y, z = blockIdx.z;
  const bf16_t* A = p.A;
  const bf16_t* Bt = p.Bt;
  const float* bias = p.bias;
  if constexpr (MODE == 0){
    Bt += (size_t)z*Hn*Hn; bias += z*Hn;
  } else {
    Bt += (size_t)z*Hn*Hn; bias += z*Hn; A += (size_t)z*Bn*Sn*Hn;
  }
  const int Ks = p.Kstride;
  const int NT = p.Kloc >> 5;

  __shared__ bf16_t As[2][128*32];
  __shared__ bf16_t Bs[2][128*32];
  const int tid = threadIdx.x, lane = tid & 63, w = tid >> 6;
  const int wr = (w >> 1) * 64, wc = (w & 1) * 64;
  const int lane15 = lane & 15, kg = lane >> 4;

  const bf16_t* aptr[2];
  const bf16_t* bptr[2];
  #pragma unroll
  for (int i = 0; i < 2; ++i){
    int ch = tid + i*256;
    int row = ch >> 2, kc = (ch & 3) * 8;
    aptr[i] = A  + (size_t)(mt*128 + row) * Ks + kc;
    bptr[i] = Bt + (size_t)(nt*128 + row) * Ks + kc;
  }

  const f32x4 fz = {0.f,0.f,0.f,0.f};
  f32x4 acc[4][4];
  #pragma unroll
  for (int m = 0; m < 4; ++m)
    #pragma unroll
    for (int n = 0; n < 4; ++n) acc[m][n] = fz;

  #pragma unroll
  for (int i = 0; i < 2; ++i){
    gload16(aptr[i], &As[0][(tid + i*256)*8]);
    gload16(bptr[i], &Bs[0][(tid + i*256)*8]);
  }
  __syncthreads();

  int cur = 0;
  for (int t = 0; t < NT; ++t){
    if (t + 1 < NT){
      int k1 = (t+1) * 32;
      #pragma unroll
      for (int i = 0; i < 2; ++i){
        gload16(aptr[i] + k1, &As[cur^1][(tid + i*256)*8]);
        gload16(bptr[i] + k1, &Bs[cur^1][(tid + i*256)*8]);
      }
    }
    bf16x8 af[4], bfr[4];
    #pragma unroll
    for (int m = 0; m < 4; ++m) af[m]  = *(const bf16x8*)(&As[cur][(wr + m*16 + lane15)*32 + kg*8]);
    #pragma unroll
    for (int n = 0; n < 4; ++n)  bfr[n] = *(const bf16x8*)(&Bs[cur][(wc + n*16 + lane15)*32 + kg*8]);
    #pragma unroll
    for (int m = 0; m < 4; ++m)
      #pragma unroll
      for (int n = 0; n < 4; ++n)
        acc[m][n] = mfma16(af[m], bfr[n], acc[m][n]);
    __syncthreads();
    cur ^= 1;
  }

  if constexpr (MODE == 0){
    bf16_t* outp = p.bfout + (size_t)z * (Bn*NHn*Sn*DHn);
    if (z < 4){
      #pragma unroll
      for (int m = 0; m < 4; ++m){
        int row0 = mt*128 + wr + m*16 + kg*4;
        #pragma unroll
        for (int n = 0; n < 4; ++n){
          int col = nt*128 + wc + n*16 + lane15;
          int nh = col >> 6, dh = col & 63;
          float bv = bias[col];
          f32x4 v = acc[m][n];
          #pragma unroll
          for (int r = 0; r < 4; ++r){
            int tk = row0 + r;
            int bb = tk >> 10, s = tk & 1023;
            outp[((size_t)(bb*NHn + nh)*Sn + s)*DHn + dh] = (bf16_t)(v[r] + bv);
          }
        }
      }
    } else {
      #pragma unroll
      for (int m = 0; m < 4; ++m){
        int row0 = mt*128 + wr + m*16 + kg*4;
        int bb = row0 >> 10, s = row0 & 1023;
        #pragma unroll
        for (int n = 0; n < 4; ++n){
          int col = nt*128 + wc + n*16 + lane15;
          int nh = col >> 6, dh = col & 63;
          float bv = bias[col];
          f32x4 v = acc[m][n];
          bf16x4 pk;
          pk[0] = (bf16_t)(v[0] + bv);
          pk[1] = (bf16_t)(v[1] + bv);
          pk[2] = (bf16_t)(v[2] + bv);
          pk[3] = (bf16_t)(v[3] + bv);
          *(bf16x4*)(outp + ((size_t)(bb*NHn + nh)*DHn + dh)*Sn + s) = pk;
        }
      }
    }
  } else {
    float* outp = p.fout + (size_t)z * Tn * Hn;
    #pragma unroll
    for (int m = 0; m < 4; ++m){
      int row0 = mt*128 + wr + m*16 + kg*4;
      #pragma unroll
      for (int n = 0; n < 4; ++n){
        int col = nt*128 + wc + n*16 + lane15;
        float bv = bias[col];
        f32x4 v = acc[m][n];
        #pragma unroll
        for (int r = 0; r < 4; ++r)
          outp[(size_t)(row0 + r)*Hn + col] = v[r] + bv;
      }
    }
  }
}

// ---------- MoE GEMM: 128x128 tile, 4-buffer counted-vmcnt pipeline (T4) ----------
// Same R8/R13 work decode; K-loop: raw s_barrier + s_waitcnt vmcnt(4), prefetch depth 2.
// Invariant at iter t's wait: outstanding loads (my wave) <= {STAGE(t+1), STAGE(t+2)} = 8;
// vmcnt(4) forces STAGE(t+1) landed, lets STAGE(t+2) fly across the barrier.
// STAGE(t+3) issued AFTER the barrier into buf[(t+3)&3] (distinct mod 4 from t,t+1,t+2).
template<int MODE>
__global__ __launch_bounds__(256)
void moe_k(GP p){
  const int bid = blockIdx.x;
  const int x = bid & 7, r = bid >> 3;
  int e, mt, nt, ks;
  if constexpr (MODE == 3){
    int slot = r >> 8, j = r & 255;     // 16 groups x 256 blocks
    int g = slot*8 + x;                 // g = e*2 + half
    e = g >> 1; ks = 0;
    mt = j >> 4;
    nt = ((g & 1) << 4) | (j & 15);
  } else {
    int slot = r >> 7, j = r & 127;     // 32 groups x 128 blocks
    int g = slot*8 + x;                 // g = e*4 + ks
    e = g >> 2; ks = g & 3;
    mt = j >> 3; nt = j & 7;
  }
  const int cnt = p.counts[e];
  if (mt * 128 >= cnt) return;          // block-uniform, before any barrier
  const int* list = p.list + e * Tn;
  int off = 0;
  #pragma unroll
  for (int q = 0; q < En; ++q) off += (q < e) ? p.counts[q] : 0;

  const int Ks    = (MODE == 3) ? Hn : Fn;
  const int kbase = (MODE == 3) ? 0 : ks * (Fn / KSPLIT);
  const int NT    = 32;
  const bf16_t* Bt = p.Bt + (size_t)e * Fn * Hn;
  const float* bias = p.bias + ((MODE == 3) ? e*Fn : e*Hn);

  __shared__ bf16_t As[4][128*32];
  __shared__ bf16_t Bs[4][128*32];
  const int tid = threadIdx.x, lane = tid & 63, w = tid >> 6;
  const int wr = (w >> 1) * 64, wc = (w & 1) * 64;
  const int lane15 = lane & 15, kg = lane >> 4;

  const bf16_t* aptr[2];
  const bf16_t* bptr[2];
  #pragma unroll
  for (int i = 0; i < 2; ++i){
    int ch = tid + i*256;
    int row = ch >> 2, kc = (ch & 3) * 8;
    int gi = mt*128 + row; if (gi >= cnt) gi = cnt - 1;
    int ar = (MODE == 3) ? (list[gi] >> 1) : (off + gi);
    aptr[i] = p.A + (size_t)ar * Ks + kbase + kc;
    bptr[i] = Bt + (size_t)(nt*128 + row) * Ks + kbase + kc;
  }

  const f32x4 fz = {0.f,0.f,0.f,0.f};
  f32x4 acc[4][4];
  #pragma unroll
  for (int m = 0; m < 4; ++m)
    #pragma unroll
    for (int n = 0; n < 4; ++n) acc[m][n] = fz;

  // STAGE(T) into buffer B: 4 loads/thread (2 A-chunks + 2 B-chunks)
  #define STAGE_T(T, B) do { int k1_ = (T)*32;                       \
    gload16(aptr[0] + k1_, &As[B][(tid)*8]);                         \
    gload16(aptr[1] + k1_, &As[B][(tid + 256)*8]);                   \
    gload16(bptr[0] + k1_, &Bs[B][(tid)*8]);                         \
    gload16(bptr[1] + k1_, &Bs[B][(tid + 256)*8]); } while (0)

  // prologue: depth-2 pipeline fill
  STAGE_T(0, 0);
  STAGE_T(1, 1);
  STAGE_T(2, 2);
  asm volatile("s_waitcnt vmcnt(8)" ::: "memory");   // tile 0 landed; 1,2 in flight
  __builtin_amdgcn_s_barrier();
  __builtin_amdgcn_sched_barrier(0);

  for (int t = 0; t < NT; ++t){
    const int cur = t & 3;
    bf16x8 af[4], bfr[4];
    #pragma unroll
    for (int m = 0; m < 4; ++m) af[m]  = *(const bf16x8*)(&As[cur][(wr + m*16 + lane15)*32 + kg*8]);
    #pragma unroll
    for (int n = 0; n < 4; ++n)  bfr[n] = *(const bf16x8*)(&Bs[cur][(wc + n*16 + lane15)*32 + kg*8]);
    #pragma unroll
    for (int m = 0; m < 4; ++m)
      #pragma unroll
      for (int n = 0; n < 4; ++n)
        acc[m][n] = mfma16(af[m], bfr[n], acc[m][n]);
    // counted wait: force STAGE(t+1) landed; STAGE(t+2) may stay in flight across barrier
    asm volatile("s_waitcnt vmcnt(4)" ::: "memory");
    __builtin_amdgcn_s_barrier();
    __builtin_amdgcn_sched_barrier(0);
    if (t + 3 < NT) STAGE_T(t + 3, (t + 3) & 3);
  }
  #undef STAGE_T

  if constexpr (MODE == 3){
    #pragma unroll
    for (int m = 0; m < 4; ++m){
      int row0 = mt*128 + wr + m*16 + kg*4;
      #pragma unroll
      for (int n = 0; n < 4; ++n){
        int col = nt*128 + wc + n*16 + lane15;
        float bv = bias[col];
        f32x4 v = acc[m][n];
        #pragma unroll
        for (int r = 0; r < 4; ++r){
          int gi = row0 + r;
          if (gi < cnt)
            p.bfout[(size_t)(off + gi)*Fn + col] = (bf16_t)gelu_f(v[r] + bv);
        }
      }
    }
  } else {
    bf16_t* outp = p.bfout + (size_t)ks * An * Hn;
    bool addb = (ks == 0);
    #pragma unroll
    for (int m = 0; m < 4; ++m){
      int row0 = mt*128 + wr + m*16 + kg*4;
      #pragma unroll
      for (int n = 0; n < 4; ++n){
        int col = nt*128 + wc + n*16 + lane15;
        float bv = addb ? bias[col] : 0.f;
        f32x4 v = acc[m][n];
        #pragma unroll
        for (int r = 0; r < 4; ++r){
          int gi = row0 + r;
          if (gi < cnt){
            int aid = list[gi];
            outp[(size_t)aid*Hn + col] = (bf16_t)(v[r] + bv);
          }
        }
      }
    }
  }
}

// ---------- flash attention: 4 waves/block, LDS-staged K/V (dbuf, swizzled), swapped QK^T ----------
__global__ __launch_bounds__(256)
void attn_k(const bf16_t* __restrict__ qh, const bf16_t* __restrict__ kh,
            const bf16_t* __restrict__ vtb, const int* __restrict__ amask,
            bf16_t* __restrict__ ctxb){
  int z  = blockIdx.x;          // head: lvl*32 + bb*16 + nh
  int qb = blockIdx.y;
  int lvl = z >> 5, bb = (z >> 4) & 1, nh = z & 15;
  int tid = threadIdx.x, lane = tid & 63, w = tid >> 6;
  int lane15 = lane & 15, kg = lane >> 4;
  const bf16_t* Q  = qh  + (size_t)z * Sn * DHn;
  const bf16_t* Kp = kh  + (size_t)z * Sn * DHn;
  const bf16_t* Vt = vtb + (size_t)z * DHn * Sn;
  const int* mrow = amask + bb * Sn;
  __shared__ bf16_t Ks[2][32*64];
  __shared__ bf16_t Vs[2][64*32];
  __shared__ float bias_lds[Sn];
  __shared__ bf16_t p_lds[4][16*40];
  {
    int4 mv = ((const int4*)mrow)[tid];
    float4 bv;
    bv.x = mv.x ? 0.f : -1e9f;
    bv.y = mv.y ? 0.f : -1e9f;
    bv.z = mv.z ? 0.f : -1e9f;
    bv.w = mv.w ? 0.f : -1e9f;
    ((float4*)bias_lds)[tid] = bv;
  }
  int krow = w*8 + (lane >> 3);
  const bf16_t* ksrc = Kp + (size_t)krow*DHn + (((lane&7) ^ (krow&7)) << 3);
  int vrow = w*16 + (lane >> 2);
  const bf16_t* vsrc = Vt + (size_t)vrow*Sn + ((((lane&3) ^ ((vrow>>2)&3))) << 3);
  bf16_t* kdst[2] = { &Ks[0][w*512 + lane*8], &Ks[1][w*512 + lane*8] };
  bf16_t* vdst[2] = { &Vs[0][w*512 + lane*8], &Vs[1][w*512 + lane*8] };

  const f32x4 fz = {0.f,0.f,0.f,0.f};
  int qt = qb*4 + w;
  int qr = qt*16 + lane15;
  bf16x8 qa0 = *(const bf16x8*)(Q + (size_t)qr*DHn + kg*8);
  bf16x8 qa1 = *(const bf16x8*)(Q + (size_t)qr*DHn + 32 + kg*8);
  f32x4 ctxa[4] = {fz, fz, fz, fz};
  float m_ln = -1e30f;
  float s_ln = 0.f;
  float m_out[4] = {-1e30f,-1e30f,-1e30f,-1e30f};

  const int kslot0 = (kg ^ (lane15 & 7));
  const int kslot1 = ((kg + 4) ^ (lane15 & 7));
  const int ka_off0 = lane15*64 + kslot0*8;
  const int ka_off1 = lane15*64 + kslot1*8;
  const int kb_off0 = (16 + lane15)*64 + kslot0*8;
  const int kb_off1 = (16 + lane15)*64 + kslot1*8;

  gload16(ksrc, kdst[0]);
  gload16(vsrc, vdst[0]);
  __syncthreads();

  for (int kc = 0; kc < 32; ++kc){
    const int cur = kc & 1;
    const bf16_t* Kb = Ks[cur];
    const bf16_t* Vb = Vs[cur];
    if (kc + 1 < 32){
      gload16(ksrc + (size_t)(kc+1)*32*DHn, kdst[cur^1]);
      gload16(vsrc + (kc+1)*32,             vdst[cur^1]);
    }
    int k0 = kc * 32;
    bf16x8 ka0 = *(const bf16x8*)(Kb + ka_off0);
    bf16x8 ka1 = *(const bf16x8*)(Kb + ka_off1);
    bf16x8 kb0 = *(const bf16x8*)(Kb + kb_off0);
    bf16x8 kb1 = *(const bf16x8*)(Kb + kb_off1);
    f32x4 sA = mfma16(ka1, qa1, mfma16(ka0, qa0, fz));
    f32x4 sB = mfma16(kb1, qa1, mfma16(kb0, qa0, fz));
    float4 biasA = *(const float4*)(bias_lds + k0 + kg*4);
    float4 biasB = *(const float4*)(bias_lds + k0 + 16 + kg*4);
    float sv[8];
    sv[0] = sA[0]*0.125f + biasA.x;
    sv[1] = sA[1]*0.125f + biasA.y;
    sv[2] = sA[2]*0.125f + biasA.z;
    sv[3] = sA[3]*0.125f + biasA.w;
    sv[4] = sB[0]*0.125f + biasB.x;
    sv[5] = sB[1]*0.125f + biasB.y;
    sv[6] = sB[2]*0.125f + biasB.z;
    sv[7] = sB[3]*0.125f + biasB.w;
    float mx = fmaxf(fmaxf(fmaxf(sv[0],sv[1]),fmaxf(sv[2],sv[3])),
                     fmaxf(fmaxf(sv[4],sv[5]),fmaxf(sv[6],sv[7])));
    mx = fmaxf(mx, __shfl_xor(mx, 16));
    mx = fmaxf(mx, __shfl_xor(mx, 32));
    if (!__all(mx <= m_ln)){
      float mnew = fmaxf(m_ln, mx);
      s_ln *= __expf(m_ln - mnew);
      #pragma unroll
      for (int r = 0; r < 4; ++r){
        float mo = __shfl(mnew, kg*4 + r);
        float corr = __expf(m_out[r] - mo);
        ctxa[0][r] *= corr; ctxa[1][r] *= corr; ctxa[2][r] *= corr; ctxa[3][r] *= corr;
        m_out[r] = mo;
      }
      m_ln = mnew;
    }
    float pv[8];
    #pragma unroll
    for (int j = 0; j < 8; ++j){ pv[j] = __expf(sv[j] - m_ln); s_ln += pv[j]; }
    bf16_t* pr = p_lds[w] + lane15*40;
    *(bf16x2*)(pr + kg*4)          = (bf16x2){(bf16_t)pv[0], (bf16_t)pv[1]};
    *(bf16x2*)(pr + kg*4 + 2)      = (bf16x2){(bf16_t)pv[2], (bf16_t)pv[3]};
    *(bf16x2*)(pr + 16 + kg*4)     = (bf16x2){(bf16_t)pv[4], (bf16_t)pv[5]};
    *(bf16x2*)(pr + 16 + kg*4 + 2) = (bf16x2){(bf16_t)pv[6], (bf16_t)pv[7]};
    bf16x8 paf = *(const bf16x8*)(p_lds[w] + lane15*40 + kg*8);
    #pragma unroll
    for (int df = 0; df < 4; ++df){
      int r = df*16 + lane15;
      bf16x8 vbf = *(const bf16x8*)(Vb + r*32 + ((kg ^ ((r>>2)&3)) << 3));
      ctxa[df] = mfma16(paf, vbf, ctxa[df]);
    }
    __syncthreads();
  }
  s_ln += __shfl_xor(s_ln, 16);
  s_ln += __shfl_xor(s_ln, 32);
  #pragma unroll
  for (int r = 0; r < 4; ++r){
    float inv = 1.f / __shfl(s_ln, kg*4 + r);
    int srow = qt*16 + kg*4 + r;
    #pragma unroll
    for (int df = 0; df < 4; ++df){
      int d = df*16 + lane15;
      ctxb[((size_t)(lvl*2 + bb)*Sn + srow)*Hn + nh*DHn + d] = (bf16_t)(ctxa[df][r] * inv);
    }
  }
}

// ---------- router: 1 wave / token, full fp32 LN2+logits (discrete top-2 fidelity) ----------
__global__ __launch_bounds__(64)
void router_k(const float* __restrict__ x2, const float* __restrict__ gam,
              const float* __restrict__ bet, const float* __restrict__ Wr,
              const float* __restrict__ br, float* __restrict__ gates,
              int* __restrict__ lists, int* __restrict__ counts){
  int t = blockIdx.x, lane = threadIdx.x;
  const float4* xr = (const float4*)(x2 + (size_t)t * Hn);
  float4 vbuf[4];
  float s = 0.f, ss = 0.f;
  #pragma unroll
  for (int i = 0; i < 4; ++i){
    float4 v = xr[lane + i*64];
    vbuf[i] = v;
    s  += v.x + v.y + v.z + v.w;
    ss += v.x*v.x + v.y*v.y + v.z*v.z + v.w*v.w;
  }
  #pragma unroll
  for (int mk = 1; mk < 64; mk <<= 1){ s += __shfl_xor(s, mk); ss += __shfl_xor(ss, mk); }
  float mean = s * (1.0f/Hn);
  float var  = ss * (1.0f/Hn) - mean*mean;
  float rstd = rsqrtf(var + 1e-5f);
  float a[8] = {0,0,0,0,0,0,0,0};
  #pragma unroll
  for (int i = 0; i < 4; ++i){
    int c = (lane + i*64) * 4;
    float4 v = vbuf[i];
    float xn[4] = {
      (v.x-mean)*rstd*gam[c+0] + bet[c+0],
      (v.y-mean)*rstd*gam[c+1] + bet[c+1],
      (v.z-mean)*rstd*gam[c+2] + bet[c+2],
      (v.w-mean)*rstd*gam[c+3] + bet[c+3]};
    #pragma unroll
    for (int j = 0; j < 4; ++j){
      const float* w = Wr + (size_t)(c + j) * En;
      #pragma unroll
      for (int e8 = 0; e8 < 8; ++e8) a[e8] += xn[j] * w[e8];
    }
  }
  #pragma unroll
  for (int e8 = 0; e8 < 8; ++e8)
    #pragma unroll
    for (int mk = 1; mk < 64; mk <<= 1) a[e8] += __shfl_xor(a[e8], mk);
  if (lane == 0){
    float lg[8]; float mx = -1e30f;
    #pragma unroll
    for (int e8 = 0; e8 < 8; ++e8){ lg[e8] = a[e8] + br[e8]; mx = fmaxf(mx, lg[e8]); }
    float p[8];
    #pragma unroll
    for (int e8 = 0; e8 < 8; ++e8) p[e8] = __expf(lg[e8] - mx);
    int i0 = 0; float v0 = p[0];
    #pragma unroll
    for (int e8 = 1; e8 < 8; ++e8) if (p[e8] > v0){ v0 = p[e8]; i0 = e8; }
    int i1 = -1; float v1 = -1.f;
    #pragma unroll
    for (int e8 = 0; e8 < 8; ++e8) if (e8 != i0 && p[e8] > v1){ v1 = p[e8]; i1 = e8; }
    float g0 = v0 / (v0 + v1), g1 = v1 / (v0 + v1);
    gates[2*t] = g0; gates[2*t+1] = g1;
    int s0 = atomicAdd(&counts[i0], 1); lists[i0*Tn + s0] = 2*t;
    int s1 = atomicAdd(&counts[i1], 1); lists[i1*Tn + s1] = 2*t + 1;
  }
}

// ---------- final combine: out = x2 + g0*sum_ks P[ks][2t] + g1*sum_ks P[ks][2t+1] ----------
__global__ __launch_bounds__(256)
void comb_k(const float* __restrict__ x2, const bf16_t* __restrict__ P,
            const float* __restrict__ gates, float* __restrict__ out){
  int t = blockIdx.x, i = threadIdx.x;
  float g0 = gates[2*t], g1 = gates[2*t+1];
  const size_t PS = (size_t)An * Hn;
  f32x4 s0 = {0,0,0,0}, s1 = {0,0,0,0};
  #pragma unroll
  for (int ks = 0; ks < KSPLIT; ++ks){
    bf16x4 u0 = *(const bf16x4*)(P + ks*PS + (size_t)(2*t)*Hn + i*4);
    bf16x4 u1 = *(const bf16x4*)(P + ks*PS + (size_t)(2*t+1)*Hn + i*4);
    #pragma unroll
    for (int j = 0; j < 4; ++j){ s0[j] += (float)u0[j]; s1[j] += (float)u1[j]; }
  }
  f32x4 va = ((const f32x4*)(x2 + (size_t)t*Hn))[i];
  f32x4 o = va + g0*s0 + g1*s1;
  ((f32x4*)(out + (size_t)t*Hn))[i] = o;
}

extern "C" void kernel_launch(void* const* d_in, const int* in_sizes, int n_in,
                              void* d_out, int out_size, void* d_ws, size_t ws_size,
                              hipStream_t stream)
{
  const float* x    = (const float*)d_in[0];
  const int* amask  = (const int*)d_in[1];
  const float* ln1g = (const float*)d_in[2];
  const float* ln1b = (const float*)d_in[3];
  const float* ln2g = (const float*)d_in[4];
  const float* ln2b = (const float*)d_in[5];
  const float* Wq   = (const float*)d_in[6];
  const float* Wk   = (const float*)d_in[7];
  const float* Wv   = (const float*)d_in[8];
  const float* Wo   = (const float*)d_in[9];
  const float* bq   = (const float*)d_in[10];
  const float* bk   = (const float*)d_in[11];
  const float* bv   = (const float*)d_in[12];
  const float* bo   = (const float*)d_in[13];
  const float* lvl  = (const float*)d_in[14];
  const float* Wr   = (const float*)d_in[15];
  const float* br   = (const float*)d_in[16];
  const float* W1   = (const float*)d_in[17];
  const float* b1   = (const float*)d_in[18];
  const float* W2   = (const float*)d_in[19];
  const float* b2   = (const float*)d_in[20];
  float* out = (float*)d_out;
  (void)in_sizes; (void)n_in; (void)out_size; (void)ws_size;

  char* wsp = (char*)d_ws;
  auto nxt = [&](size_t bytes) -> char* {
    char* r = wsp; wsp += (bytes + 255) & ~(size_t)255; return r;
  };
  bf16_t* wqkvT = (bf16_t*)nxt((size_t)6*Hn*Hn*2);    // q(l0),q(l1),k(l0),k(l1),v(l0),v(l1)
  bf16_t* woT   = (bf16_t*)nxt((size_t)Ln*Hn*Hn*2);
  bf16_t* w1t   = (bf16_t*)nxt((size_t)En*Fn*Hn*2);
  bf16_t* w2t   = (bf16_t*)nxt((size_t)En*Hn*Fn*2);
  float*  bqkv  = (float*)nxt((size_t)6*Hn*4);
  bf16_t* xn1   = (bf16_t*)nxt((size_t)Tn*Hn*2);
  bf16_t* qkvh  = (bf16_t*)nxt((size_t)6*Bn*NHn*Sn*DHn*2);
  bf16_t* ctxb  = (bf16_t*)nxt((size_t)Ln*Bn*Sn*Hn*2);
  float*  otmp  = (float*)nxt((size_t)Ln*Tn*Hn*4);
  float*  x2    = (float*)nxt((size_t)Tn*Hn*4);
  bf16_t* xn2   = (bf16_t*)nxt((size_t)Tn*Hn*2);
  float*  gates = (float*)nxt((size_t)Tn*2*4);
  int*    lists = (int*)nxt((size_t)En*Tn*4);
  int*    counts= (int*)nxt(256);
  bf16_t* hbuf  = (bf16_t*)nxt((size_t)An*Fn*2);
  bf16_t* ybuf  = (bf16_t*)nxt((size_t)KSPLIT*An*Hn*2);

  hipMemsetAsync(counts, 0, En*sizeof(int), stream);
  hipMemcpyAsync(bqkv,          bq, (size_t)Ln*Hn*4, hipMemcpyDeviceToDevice, stream);
  hipMemcpyAsync(bqkv + 2*Hn,   bk, (size_t)Ln*Hn*4, hipMemcpyDeviceToDevice, stream);
  hipMemcpyAsync(bqkv + 4*Hn,   bv, (size_t)Ln*Hn*4, hipMemcpyDeviceToDevice, stream);

  // weight transpose+convert (64x64 tiles)
  tcvt_k<<<dim3(16,16,Ln), 256, 0, stream>>>(Wq, wqkvT,            Hn, Hn);
  tcvt_k<<<dim3(16,16,Ln), 256, 0, stream>>>(Wk, wqkvT + 2*Hn*Hn,  Hn, Hn);
  tcvt_k<<<dim3(16,16,Ln), 256, 0, stream>>>(Wv, wqkvT + 4*Hn*Hn,  Hn, Hn);
  tcvt_k<<<dim3(16,16,Ln), 256, 0, stream>>>(Wo, woT,              Hn, Hn);
  tcvt_k<<<dim3(Fn/64, Hn/64, En), 256, 0, stream>>>(W1, w1t, Hn, Fn);
  tcvt_k<<<dim3(Hn/64, Fn/64, En), 256, 0, stream>>>(W2, w2t, Fn, Hn);

  ln_k<<<Tn, 256, 0, stream>>>(x, ln1g, ln1b, xn1);

  { GP g{};   // QKV: one dispatch, z = which*2+l in [0,6)
    g.A = xn1; g.Bt = wqkvT; g.bias = bqkv; g.bfout = qkvh;
    g.Kstride = Hn; g.Kloc = Hn;
    gemm_k<0><<<dim3(8,16,6), 256, 0, stream>>>(g); }

  {
    const bf16_t* qh = qkvh;
    const bf16_t* kh = qkvh + (size_t)2*Bn*NHn*Sn*DHn;
    const bf16_t* vt = qkvh + (size_t)4*Bn*NHn*Sn*DHn;
    attn_k<<<dim3(Ln*Bn*NHn, Sn/64), 256, 0, stream>>>(qh, kh, vt, amask, ctxb);
  }

  { GP g{};   // O-proj both levels, z = l
    g.A = ctxb; g.Bt = woT; g.bias = bo; g.fout = otmp;
    g.Kstride = Hn; g.Kloc = Hn;
    gemm_k<1><<<dim3(8,16,2), 256, 0, stream>>>(g); }

  res_ln2_k<<<Tn, 256, 0, stream>>>(x, otmp, otmp + (size_t)Tn*Hn, lvl,
                                    ln2g, ln2b, x2, xn2);
  router_k<<<Tn, 64, 0, stream>>>(x2, ln2g, ln2b, Wr, br, gates, lists, counts);

  { GP g{};   // FFN1: 4-buffer counted-vmcnt pipeline, dense hbuf out
    g.A = xn2; g.Bt = w1t; g.bias = b1; g.bfout = hbuf;
    g.list = lists; g.counts = counts;
    moe_k<3><<<dim3(4096,1,1), 256, 0, stream>>>(g); }
  { GP g{};   // FFN2: 4-buffer counted-vmcnt pipeline, KSPLIT=4, dense A, bf16 partials
    g.A = hbuf; g.Bt = w2t; g.bfout = ybuf; g.bias = b2;
    g.list = lists; g.counts = counts;
    moe_k<4><<<dim3(4096,1,1), 256, 0, stream>>>(g); }

  comb_k<<<Tn, 256, 0, stream>>>(x2, ybuf, gates, out);
}

// Round 16
// 483.372 us; speedup vs baseline: 1.1255x; 1.1255x over previous
//
#include <hip/hip_runtime.h>
#include <hip/hip_bf16.h>
#include <stdint.h>

#define Hn   1024
#define NHn  16
#define DHn  64
#define Ln   2
#define En   8
#define Fn   4096
#define Bn   2
#define Sn   1024
#define Tn   2048   // B*S
#define An   4096   // assignments = Tn*2
#define KSPLIT 4

typedef __bf16 bf16_t;
typedef __bf16 bf16x2 __attribute__((ext_vector_type(2)));
typedef __bf16 bf16x4 __attribute__((ext_vector_type(4)));
typedef __bf16 bf16x8 __attribute__((ext_vector_type(8)));
typedef float  f32x4  __attribute__((ext_vector_type(4)));

__device__ __forceinline__ f32x4 mfma16(bf16x8 a, bf16x8 b, f32x4 c){
  return __builtin_amdgcn_mfma_f32_16x16x32_bf16(a, b, c, 0, 0, 0);
}
__device__ __forceinline__ void gload16(const void* gsrc, void* ldst){
  __builtin_amdgcn_global_load_lds((const __attribute__((address_space(1))) void*)gsrc,
                                   (__attribute__((address_space(3))) void*)ldst, 16, 0, 0);
}
__device__ __forceinline__ float gelu_f(float x){
  float u = 0.7978845608028654f * (x + 0.044715f * x * x * x);
  return 0.5f * x * (1.0f + tanhf(u));
}

// ---------- transpose + fp32->bf16 (vectorized): dst[c][r] = (bf16)src[r][c] ----------
__global__ __launch_bounds__(256)
void tcvt_k(const float* __restrict__ src, bf16_t* __restrict__ dst, int R, int C){
  __shared__ float tile[64][68];
  size_t moff = (size_t)blockIdx.z * R * C;
  src += moff; dst += moff;
  int c0 = blockIdx.x * 64, r0 = blockIdx.y * 64;
  int tid = threadIdx.x;
  int tx = tid & 15, ty = tid >> 4;
  #pragma unroll
  for (int i = 0; i < 4; ++i){
    float4 v = *(const float4*)(src + (size_t)(r0 + ty + i*16) * C + c0 + tx*4);
    *(float4*)&tile[ty + i*16][tx*4] = v;
  }
  __syncthreads();
  int c = tid >> 2, rq = tid & 3;
  #pragma unroll
  for (int i = 0; i < 2; ++i){
    int rr = (rq + i*4) * 8;
    bf16x8 pk;
    #pragma unroll
    for (int j = 0; j < 8; ++j) pk[j] = (bf16_t)tile[rr + j][c];
    *(bf16x8*)(dst + (size_t)(c0 + c) * R + r0 + rr) = pk;
  }
}

// ---------- LayerNorm (LN1): one block per row ----------
__global__ __launch_bounds__(256)
void ln_k(const float* __restrict__ x, const float* __restrict__ gam,
          const float* __restrict__ bet, bf16_t* __restrict__ out){
  int row = blockIdx.x;
  const float4* xr = (const float4*)(x + (size_t)row * Hn);
  int t = threadIdx.x, lane = t & 63, w = t >> 6;
  float4 v = xr[t];
  float s  = v.x + v.y + v.z + v.w;
  float ss = v.x*v.x + v.y*v.y + v.z*v.z + v.w*v.w;
  #pragma unroll
  for (int mk = 1; mk < 64; mk <<= 1){ s += __shfl_xor(s, mk); ss += __shfl_xor(ss, mk); }
  __shared__ float r1[4], r2[4];
  if (lane == 0){ r1[w] = s; r2[w] = ss; }
  __syncthreads();
  float S1 = r1[0]+r1[1]+r1[2]+r1[3];
  float S2 = r2[0]+r2[1]+r2[2]+r2[3];
  float mean = S1 * (1.0f/Hn);
  float var  = S2 * (1.0f/Hn) - mean*mean;
  float rstd = rsqrtf(var + 1e-5f);
  int c = t * 4;
  bf16_t* o = out + (size_t)row * Hn + c;
  o[0] = (bf16_t)((v.x-mean)*rstd*gam[c+0] + bet[c+0]);
  o[1] = (bf16_t)((v.y-mean)*rstd*gam[c+1] + bet[c+1]);
  o[2] = (bf16_t)((v.z-mean)*rstd*gam[c+2] + bet[c+2]);
  o[3] = (bf16_t)((v.w-mean)*rstd*gam[c+3] + bet[c+3]);
}

// ---------- fused: x2 = x + w0*o0 + w1*o1 ; xn2 = bf16(LN2(x2)) ----------
__global__ __launch_bounds__(256)
void res_ln2_k(const float* __restrict__ x, const float* __restrict__ o0,
               const float* __restrict__ o1, const float* __restrict__ lvl,
               const float* __restrict__ gam, const float* __restrict__ bet,
               float* __restrict__ x2, bf16_t* __restrict__ xn2){
  int row = blockIdx.x, t = threadIdx.x, lane = t & 63, w = t >> 6;
  float l0 = lvl[0], l1 = lvl[1];
  float mx = fmaxf(l0, l1);
  float e0 = __expf(l0 - mx), e1 = __expf(l1 - mx);
  float inv = 1.f / (e0 + e1);
  float w0 = e0 * inv, w1 = e1 * inv;
  size_t base = (size_t)row * Hn;
  float4 xv = ((const float4*)(x  + base))[t];
  float4 a0 = ((const float4*)(o0 + base))[t];
  float4 a1 = ((const float4*)(o1 + base))[t];
  float4 v;
  v.x = xv.x + w0*a0.x + w1*a1.x;
  v.y = xv.y + w0*a0.y + w1*a1.y;
  v.z = xv.z + w0*a0.z + w1*a1.z;
  v.w = xv.w + w0*a0.w + w1*a1.w;
  ((float4*)(x2 + base))[t] = v;
  float s  = v.x + v.y + v.z + v.w;
  float ss = v.x*v.x + v.y*v.y + v.z*v.z + v.w*v.w;
  #pragma unroll
  for (int mk = 1; mk < 64; mk <<= 1){ s += __shfl_xor(s, mk); ss += __shfl_xor(ss, mk); }
  __shared__ float r1[4], r2[4];
  if (lane == 0){ r1[w] = s; r2[w] = ss; }
  __syncthreads();
  float S1 = r1[0]+r1[1]+r1[2]+r1[3];
  float S2 = r2[0]+r2[1]+r2[2]+r2[3];
  float mean = S1 * (1.0f/Hn);
  float var  = S2 * (1.0f/Hn) - mean*mean;
  float rstd = rsqrtf(var + 1e-5f);
  int c = t * 4;
  bf16_t* o = xn2 + base + c;
  o[0] = (bf16_t)((v.x-mean)*rstd*gam[c+0] + bet[c+0]);
  o[1] = (bf16_t)((v.y-mean)*rstd*gam[c+1] + bet[c+1]);
  o[2] = (bf16_t)((v.z-mean)*rstd*gam[c+2] + bet[c+2]);
  o[3] = (bf16_t)((v.w-mean)*rstd*gam[c+3] + bet[c+3]);
}

// ---------- GEMM template: 128x128 tile, BK=32, 2-phase dbuf prefetch ----------
// MODE 0: QKV proj, z in [0,6): z<4 -> q/k [z][hh][s][d]; z>=4 -> V^T [z][hh][d][s]
// MODE 1: O-proj,   z=l in [0,2): out fp32 otmp[l] = acc + bias
// MODE 3: MoE FFN1, 1D grid, XCD-clustered (e, n-half) groups; h[aid]=gelu(acc+bias)
// MODE 4: MoE FFN2, 1D grid, XCD-clustered (e, ks) groups; bf16 partial out
struct GP {
  const bf16_t* A;
  const bf16_t* Bt;
  const float*  bias;
  float*        fout;
  bf16_t*       bfout;
  const int*    list;
  const int*    counts;
  int Kstride;
  int Kloc;
};

template<int MODE>
__global__ __launch_bounds__(256)
void gemm_k(GP p){
  constexpr int BM  = 128;
  constexpr int ACH = BM / 64;
  constexpr int WRT = BM / 2;
  constexpr int Mf  = WRT / 16;
  // block-index decode; MODE 3/4 use 1D grid with XCD-clustered groups:
  // all blocks of one weight-panel group share bid%8 -> same XCD -> panel L2-resident.
  int nt, mt, z;
  if constexpr (MODE == 3){
    int bid = blockIdx.x;
    int x = bid & 7, r = bid >> 3;
    int slot = r >> 8, j = r & 255;     // 16 groups x 256 blocks
    int g = slot*8 + x;                 // g = e*2 + half
    z = g >> 1;
    mt = j >> 4;
    nt = ((g & 1) << 4) | (j & 15);
  } else if constexpr (MODE == 4){
    int bid = blockIdx.x;
    int x = bid & 7, r = bid >> 3;
    int slot = r >> 7, j = r & 127;     // 32 groups x 128 blocks
    int g = slot*8 + x;                 // g = e*4 + ks
    z = (g >> 2) * KSPLIT + (g & 3);
    mt = j >> 3;
    nt = j & 7;
  } else {
    nt = blockIdx.x; mt = blockIdx.y; z = blockIdx.z;
  }
  const bf16_t* A = p.A;
  const bf16_t* Bt = p.Bt;
  const float* bias = p.bias;
  const int* list = nullptr;
  int cnt = 0x7fffffff;
  int kbase = 0;
  if constexpr (MODE == 0){
    Bt += (size_t)z*Hn*Hn; bias += z*Hn;
  } else if constexpr (MODE == 1){
    Bt += (size_t)z*Hn*Hn; bias += z*Hn; A += (size_t)z*Bn*Sn*Hn;
  } else if constexpr (MODE == 3){
    cnt = p.counts[z];
    if (mt * BM >= cnt) return;
    list = p.list + z * Tn;
    Bt += (size_t)z*Fn*Hn; bias += z*Fn;
  } else { // MODE 4
    int e = z >> 2;
    cnt = p.counts[e];
    if (mt * BM >= cnt) return;
    list = p.list + e * Tn;
    Bt += (size_t)e*Hn*Fn; bias += e*Hn;
    kbase = (z & 3) * (Fn / KSPLIT);
  }
  const int Ks = p.Kstride;
  const int NT = p.Kloc >> 5;

  __shared__ bf16_t As[2][BM*32];
  __shared__ bf16_t Bs[2][128*32];
  const int tid = threadIdx.x, lane = tid & 63, w = tid >> 6;
  const int wr = (w >> 1) * WRT, wc = (w & 1) * 64;
  const int lane15 = lane & 15, kg = lane >> 4;

  const bf16_t* aptr[ACH];
  int achk[ACH];
  #pragma unroll
  for (int i = 0; i < ACH; ++i){
    int ch = tid + i*256;
    achk[i] = ch;
    int row = ch >> 2, kc = (ch & 3) * 8;
    int ar;
    if constexpr (MODE == 3){ int g = mt*BM + row; if (g >= cnt) g = cnt - 1; ar = list[g] >> 1; }
    else if constexpr (MODE == 4){ int g = mt*BM + row; if (g >= cnt) g = cnt - 1; ar = list[g]; }
    else ar = mt*BM + row;
    aptr[i] = A + (size_t)ar * Ks + kbase + kc;
  }
  const bf16_t* bptr[2];
  int bchk[2];
  #pragma unroll
  for (int i = 0; i < 2; ++i){
    int ch = tid + i*256;
    bchk[i] = ch;
    int row = ch >> 2, kc = (ch & 3) * 8;
    bptr[i] = Bt + (size_t)(nt*128 + row) * Ks + kbase + kc;
  }

  const f32x4 fz = {0.f,0.f,0.f,0.f};
  f32x4 acc[Mf][4];
  #pragma unroll
  for (int m = 0; m < Mf; ++m)
    #pragma unroll
    for (int n = 0; n < 4; ++n) acc[m][n] = fz;

  #pragma unroll
  for (int i = 0; i < ACH; ++i) gload16(aptr[i], &As[0][achk[i]*8]);
  #pragma unroll
  for (int i = 0; i < 2; ++i)   gload16(bptr[i], &Bs[0][bchk[i]*8]);
  __syncthreads();

  int cur = 0;
  for (int t = 0; t < NT; ++t){
    if (t + 1 < NT){
      int k1 = (t+1) * 32;
      #pragma unroll
      for (int i = 0; i < ACH; ++i) gload16(aptr[i] + k1, &As[cur^1][achk[i]*8]);
      #pragma unroll
      for (int i = 0; i < 2; ++i)   gload16(bptr[i] + k1, &Bs[cur^1][bchk[i]*8]);
    }
    bf16x8 af[Mf], bfr[4];
    #pragma unroll
    for (int m = 0; m < Mf; ++m) af[m]  = *(const bf16x8*)(&As[cur][(wr + m*16 + lane15)*32 + kg*8]);
    #pragma unroll
    for (int n = 0; n < 4; ++n)  bfr[n] = *(const bf16x8*)(&Bs[cur][(wc + n*16 + lane15)*32 + kg*8]);
    #pragma unroll
    for (int m = 0; m < Mf; ++m)
      #pragma unroll
      for (int n = 0; n < 4; ++n)
        acc[m][n] = mfma16(af[m], bfr[n], acc[m][n]);
    __syncthreads();
    cur ^= 1;
  }

  // epilogue: D layout row=(lane>>4)*4+r, col=lane&15 (m89)
  if constexpr (MODE == 0){
    bf16_t* outp = p.bfout + (size_t)z * (Bn*NHn*Sn*DHn);
    if (z < 4){
      #pragma unroll
      for (int m = 0; m < Mf; ++m){
        int row0 = mt*BM + wr + m*16 + kg*4;
        #pragma unroll
        for (int n = 0; n < 4; ++n){
          int col = nt*128 + wc + n*16 + lane15;
          int nh = col >> 6, dh = col & 63;
          float bv = bias[col];
          f32x4 v = acc[m][n];
          #pragma unroll
          for (int r = 0; r < 4; ++r){
            int tk = row0 + r;
            int bb = tk >> 10, s = tk & 1023;
            outp[((size_t)(bb*NHn + nh)*Sn + s)*DHn + dh] = (bf16_t)(v[r] + bv);
          }
        }
      }
    } else {
      #pragma unroll
      for (int m = 0; m < Mf; ++m){
        int row0 = mt*BM + wr + m*16 + kg*4;
        int bb = row0 >> 10, s = row0 & 1023;
        #pragma unroll
        for (int n = 0; n < 4; ++n){
          int col = nt*128 + wc + n*16 + lane15;
          int nh = col >> 6, dh = col & 63;
          float bv = bias[col];
          f32x4 v = acc[m][n];
          bf16x4 pk;
          pk[0] = (bf16_t)(v[0] + bv);
          pk[1] = (bf16_t)(v[1] + bv);
          pk[2] = (bf16_t)(v[2] + bv);
          pk[3] = (bf16_t)(v[3] + bv);
          *(bf16x4*)(outp + ((size_t)(bb*NHn + nh)*DHn + dh)*Sn + s) = pk;
        }
      }
    }
  } else if constexpr (MODE == 1){
    float* outp = p.fout + (size_t)z * Tn * Hn;
    #pragma unroll
    for (int m = 0; m < Mf; ++m){
      int row0 = mt*BM + wr + m*16 + kg*4;
      #pragma unroll
      for (int n = 0; n < 4; ++n){
        int col = nt*128 + wc + n*16 + lane15;
        float bv = bias[col];
        f32x4 v = acc[m][n];
        #pragma unroll
        for (int r = 0; r < 4; ++r)
          outp[(size_t)(row0 + r)*Hn + col] = v[r] + bv;
      }
    }
  } else if constexpr (MODE == 3){
    #pragma unroll
    for (int m = 0; m < Mf; ++m){
      int row0 = mt*BM + wr + m*16 + kg*4;
      #pragma unroll
      for (int n = 0; n < 4; ++n){
        int col = nt*128 + wc + n*16 + lane15;
        float bv = bias[col];
        f32x4 v = acc[m][n];
        #pragma unroll
        for (int r = 0; r < 4; ++r){
          int g = row0 + r;
          if (g < cnt){
            int aid = list[g];
            p.bfout[(size_t)aid*Fn + col] = (bf16_t)gelu_f(v[r] + bv);
          }
        }
      }
    }
  } else { // MODE 4
    bf16_t* outp = p.bfout + (size_t)(z & 3) * An * Hn;
    bool addb = (z & 3) == 0;
    #pragma unroll
    for (int m = 0; m < Mf; ++m){
      int row0 = mt*BM + wr + m*16 + kg*4;
      #pragma unroll
      for (int n = 0; n < 4; ++n){
        int col = nt*128 + wc + n*16 + lane15;
        float bv = addb ? bias[col] : 0.f;
        f32x4 v = acc[m][n];
        #pragma unroll
        for (int r = 0; r < 4; ++r){
          int g = row0 + r;
          if (g < cnt){
            int aid = list[g];
            outp[(size_t)aid*Hn + col] = (bf16_t)(v[r] + bv);
          }
        }
      }
    }
  }
}

// ---------- flash attention: 4 waves/block, LDS-staged K/V (dbuf, swizzled), swapped QK^T ----------
__global__ __launch_bounds__(256)
void attn_k(const bf16_t* __restrict__ qh, const bf16_t* __restrict__ kh,
            const bf16_t* __restrict__ vtb, const int* __restrict__ amask,
            bf16_t* __restrict__ ctxb){
  int z  = blockIdx.x;          // head: lvl*32 + bb*16 + nh
  int qb = blockIdx.y;
  int lvl = z >> 5, bb = (z >> 4) & 1, nh = z & 15;
  int tid = threadIdx.x, lane = tid & 63, w = tid >> 6;
  int lane15 = lane & 15, kg = lane >> 4;
  const bf16_t* Q  = qh  + (size_t)z * Sn * DHn;
  const bf16_t* Kp = kh  + (size_t)z * Sn * DHn;
  const bf16_t* Vt = vtb + (size_t)z * DHn * Sn;
  const int* mrow = amask + bb * Sn;
  __shared__ bf16_t Ks[2][32*64];
  __shared__ bf16_t Vs[2][64*32];
  __shared__ float bias_lds[Sn];
  __shared__ bf16_t p_lds[4][16*40];
  {
    int4 mv = ((const int4*)mrow)[tid];
    float4 bv;
    bv.x = mv.x ? 0.f : -1e9f;
    bv.y = mv.y ? 0.f : -1e9f;
    bv.z = mv.z ? 0.f : -1e9f;
    bv.w = mv.w ? 0.f : -1e9f;
    ((float4*)bias_lds)[tid] = bv;
  }
  int krow = w*8 + (lane >> 3);
  const bf16_t* ksrc = Kp + (size_t)krow*DHn + (((lane&7) ^ (krow&7)) << 3);
  int vrow = w*16 + (lane >> 2);
  const bf16_t* vsrc = Vt + (size_t)vrow*Sn + ((((lane&3) ^ ((vrow>>2)&3))) << 3);
  bf16_t* kdst[2] = { &Ks[0][w*512 + lane*8], &Ks[1][w*512 + lane*8] };
  bf16_t* vdst[2] = { &Vs[0][w*512 + lane*8], &Vs[1][w*512 + lane*8] };

  const f32x4 fz = {0.f,0.f,0.f,0.f};
  int qt = qb*4 + w;
  int qr = qt*16 + lane15;
  bf16x8 qa0 = *(const bf16x8*)(Q + (size_t)qr*DHn + kg*8);
  bf16x8 qa1 = *(const bf16x8*)(Q + (size_t)qr*DHn + 32 + kg*8);
  f32x4 ctxa[4] = {fz, fz, fz, fz};
  float m_ln = -1e30f;
  float s_ln = 0.f;
  float m_out[4] = {-1e30f,-1e30f,-1e30f,-1e30f};

  const int kslot0 = (kg ^ (lane15 & 7));
  const int kslot1 = ((kg + 4) ^ (lane15 & 7));
  const int ka_off0 = lane15*64 + kslot0*8;
  const int ka_off1 = lane15*64 + kslot1*8;
  const int kb_off0 = (16 + lane15)*64 + kslot0*8;
  const int kb_off1 = (16 + lane15)*64 + kslot1*8;

  gload16(ksrc, kdst[0]);
  gload16(vsrc, vdst[0]);
  __syncthreads();

  for (int kc = 0; kc < 32; ++kc){
    const int cur = kc & 1;
    const bf16_t* Kb = Ks[cur];
    const bf16_t* Vb = Vs[cur];
    if (kc + 1 < 32){
      gload16(ksrc + (size_t)(kc+1)*32*DHn, kdst[cur^1]);
      gload16(vsrc + (kc+1)*32,             vdst[cur^1]);
    }
    int k0 = kc * 32;
    bf16x8 ka0 = *(const bf16x8*)(Kb + ka_off0);
    bf16x8 ka1 = *(const bf16x8*)(Kb + ka_off1);
    bf16x8 kb0 = *(const bf16x8*)(Kb + kb_off0);
    bf16x8 kb1 = *(const bf16x8*)(Kb + kb_off1);
    f32x4 sA = mfma16(ka1, qa1, mfma16(ka0, qa0, fz));
    f32x4 sB = mfma16(kb1, qa1, mfma16(kb0, qa0, fz));
    float4 biasA = *(const float4*)(bias_lds + k0 + kg*4);
    float4 biasB = *(const float4*)(bias_lds + k0 + 16 + kg*4);
    float sv[8];
    sv[0] = sA[0]*0.125f + biasA.x;
    sv[1] = sA[1]*0.125f + biasA.y;
    sv[2] = sA[2]*0.125f + biasA.z;
    sv[3] = sA[3]*0.125f + biasA.w;
    sv[4] = sB[0]*0.125f + biasB.x;
    sv[5] = sB[1]*0.125f + biasB.y;
    sv[6] = sB[2]*0.125f + biasB.z;
    sv[7] = sB[3]*0.125f + biasB.w;
    float mx = fmaxf(fmaxf(fmaxf(sv[0],sv[1]),fmaxf(sv[2],sv[3])),
                     fmaxf(fmaxf(sv[4],sv[5]),fmaxf(sv[6],sv[7])));
    mx = fmaxf(mx, __shfl_xor(mx, 16));
    mx = fmaxf(mx, __shfl_xor(mx, 32));
    if (!__all(mx <= m_ln)){
      float mnew = fmaxf(m_ln, mx);
      s_ln *= __expf(m_ln - mnew);
      #pragma unroll
      for (int r = 0; r < 4; ++r){
        float mo = __shfl(mnew, kg*4 + r);
        float corr = __expf(m_out[r] - mo);
        ctxa[0][r] *= corr; ctxa[1][r] *= corr; ctxa[2][r] *= corr; ctxa[3][r] *= corr;
        m_out[r] = mo;
      }
      m_ln = mnew;
    }
    float pv[8];
    #pragma unroll
    for (int j = 0; j < 8; ++j){ pv[j] = __expf(sv[j] - m_ln); s_ln += pv[j]; }
    bf16_t* pr = p_lds[w] + lane15*40;
    *(bf16x2*)(pr + kg*4)          = (bf16x2){(bf16_t)pv[0], (bf16_t)pv[1]};
    *(bf16x2*)(pr + kg*4 + 2)      = (bf16x2){(bf16_t)pv[2], (bf16_t)pv[3]};
    *(bf16x2*)(pr + 16 + kg*4)     = (bf16x2){(bf16_t)pv[4], (bf16_t)pv[5]};
    *(bf16x2*)(pr + 16 + kg*4 + 2) = (bf16x2){(bf16_t)pv[6], (bf16_t)pv[7]};
    bf16x8 paf = *(const bf16x8*)(p_lds[w] + lane15*40 + kg*8);
    #pragma unroll
    for (int df = 0; df < 4; ++df){
      int r = df*16 + lane15;
      bf16x8 vbf = *(const bf16x8*)(Vb + r*32 + ((kg ^ ((r>>2)&3)) << 3));
      ctxa[df] = mfma16(paf, vbf, ctxa[df]);
    }
    __syncthreads();
  }
  s_ln += __shfl_xor(s_ln, 16);
  s_ln += __shfl_xor(s_ln, 32);
  #pragma unroll
  for (int r = 0; r < 4; ++r){
    float inv = 1.f / __shfl(s_ln, kg*4 + r);
    int srow = qt*16 + kg*4 + r;
    #pragma unroll
    for (int df = 0; df < 4; ++df){
      int d = df*16 + lane15;
      ctxb[((size_t)(lvl*2 + bb)*Sn + srow)*Hn + nh*DHn + d] = (bf16_t)(ctxa[df][r] * inv);
    }
  }
}

// ---------- router: 1 wave / token, full fp32 LN2+logits (discrete top-2 fidelity) ----------
__global__ __launch_bounds__(64)
void router_k(const float* __restrict__ x2, const float* __restrict__ gam,
              const float* __restrict__ bet, const float* __restrict__ Wr,
              const float* __restrict__ br, float* __restrict__ gates,
              int* __restrict__ lists, int* __restrict__ counts){
  int t = blockIdx.x, lane = threadIdx.x;
  const float4* xr = (const float4*)(x2 + (size_t)t * Hn);
  float4 vbuf[4];
  float s = 0.f, ss = 0.f;
  #pragma unroll
  for (int i = 0; i < 4; ++i){
    float4 v = xr[lane + i*64];
    vbuf[i] = v;
    s  += v.x + v.y + v.z + v.w;
    ss += v.x*v.x + v.y*v.y + v.z*v.z + v.w*v.w;
  }
  #pragma unroll
  for (int mk = 1; mk < 64; mk <<= 1){ s += __shfl_xor(s, mk); ss += __shfl_xor(ss, mk); }
  float mean = s * (1.0f/Hn);
  float var  = ss * (1.0f/Hn) - mean*mean;
  float rstd = rsqrtf(var + 1e-5f);
  float a[8] = {0,0,0,0,0,0,0,0};
  #pragma unroll
  for (int i = 0; i < 4; ++i){
    int c = (lane + i*64) * 4;
    float4 v = vbuf[i];
    float xn[4] = {
      (v.x-mean)*rstd*gam[c+0] + bet[c+0],
      (v.y-mean)*rstd*gam[c+1] + bet[c+1],
      (v.z-mean)*rstd*gam[c+2] + bet[c+2],
      (v.w-mean)*rstd*gam[c+3] + bet[c+3]};
    #pragma unroll
    for (int j = 0; j < 4; ++j){
      const float* w = Wr + (size_t)(c + j) * En;
      #pragma unroll
      for (int e8 = 0; e8 < 8; ++e8) a[e8] += xn[j] * w[e8];
    }
  }
  #pragma unroll
  for (int e8 = 0; e8 < 8; ++e8)
    #pragma unroll
    for (int mk = 1; mk < 64; mk <<= 1) a[e8] += __shfl_xor(a[e8], mk);
  if (lane == 0){
    float lg[8]; float mx = -1e30f;
    #pragma unroll
    for (int e8 = 0; e8 < 8; ++e8){ lg[e8] = a[e8] + br[e8]; mx = fmaxf(mx, lg[e8]); }
    float p[8];
    #pragma unroll
    for (int e8 = 0; e8 < 8; ++e8) p[e8] = __expf(lg[e8] - mx);
    int i0 = 0; float v0 = p[0];
    #pragma unroll
    for (int e8 = 1; e8 < 8; ++e8) if (p[e8] > v0){ v0 = p[e8]; i0 = e8; }
    int i1 = -1; float v1 = -1.f;
    #pragma unroll
    for (int e8 = 0; e8 < 8; ++e8) if (e8 != i0 && p[e8] > v1){ v1 = p[e8]; i1 = e8; }
    float g0 = v0 / (v0 + v1), g1 = v1 / (v0 + v1);
    gates[2*t] = g0; gates[2*t+1] = g1;
    int s0 = atomicAdd(&counts[i0], 1); lists[i0*Tn + s0] = 2*t;
    int s1 = atomicAdd(&counts[i1], 1); lists[i1*Tn + s1] = 2*t + 1;
  }
}

// ---------- final combine: out = x2 + g0*sum_ks P[ks][2t] + g1*sum_ks P[ks][2t+1] ----------
__global__ __launch_bounds__(256)
void comb_k(const float* __restrict__ x2, const bf16_t* __restrict__ P,
            const float* __restrict__ gates, float* __restrict__ out){
  int t = blockIdx.x, i = threadIdx.x;
  float g0 = gates[2*t], g1 = gates[2*t+1];
  const size_t PS = (size_t)An * Hn;
  f32x4 s0 = {0,0,0,0}, s1 = {0,0,0,0};
  #pragma unroll
  for (int ks = 0; ks < KSPLIT; ++ks){
    bf16x4 u0 = *(const bf16x4*)(P + ks*PS + (size_t)(2*t)*Hn + i*4);
    bf16x4 u1 = *(const bf16x4*)(P + ks*PS + (size_t)(2*t+1)*Hn + i*4);
    #pragma unroll
    for (int j = 0; j < 4; ++j){ s0[j] += (float)u0[j]; s1[j] += (float)u1[j]; }
  }
  f32x4 va = ((const f32x4*)(x2 + (size_t)t*Hn))[i];
  f32x4 o = va + g0*s0 + g1*s1;
  ((f32x4*)(out + (size_t)t*Hn))[i] = o;
}

extern "C" void kernel_launch(void* const* d_in, const int* in_sizes, int n_in,
                              void* d_out, int out_size, void* d_ws, size_t ws_size,
                              hipStream_t stream)
{
  const float* x    = (const float*)d_in[0];
  const int* amask  = (const int*)d_in[1];
  const float* ln1g = (const float*)d_in[2];
  const float* ln1b = (const float*)d_in[3];
  const float* ln2g = (const float*)d_in[4];
  const float* ln2b = (const float*)d_in[5];
  const float* Wq   = (const float*)d_in[6];
  const float* Wk   = (const float*)d_in[7];
  const float* Wv   = (const float*)d_in[8];
  const float* Wo   = (const float*)d_in[9];
  const float* bq   = (const float*)d_in[10];
  const float* bk   = (const float*)d_in[11];
  const float* bv   = (const float*)d_in[12];
  const float* bo   = (const float*)d_in[13];
  const float* lvl  = (const float*)d_in[14];
  const float* Wr   = (const float*)d_in[15];
  const float* br   = (const float*)d_in[16];
  const float* W1   = (const float*)d_in[17];
  const float* b1   = (const float*)d_in[18];
  const float* W2   = (const float*)d_in[19];
  const float* b2   = (const float*)d_in[20];
  float* out = (float*)d_out;
  (void)in_sizes; (void)n_in; (void)out_size; (void)ws_size;

  char* wsp = (char*)d_ws;
  auto nxt = [&](size_t bytes) -> char* {
    char* r = wsp; wsp += (bytes + 255) & ~(size_t)255; return r;
  };
  bf16_t* wqkvT = (bf16_t*)nxt((size_t)6*Hn*Hn*2);    // q(l0),q(l1),k(l0),k(l1),v(l0),v(l1)
  bf16_t* woT   = (bf16_t*)nxt((size_t)Ln*Hn*Hn*2);
  bf16_t* w1t   = (bf16_t*)nxt((size_t)En*Fn*Hn*2);
  bf16_t* w2t   = (bf16_t*)nxt((size_t)En*Hn*Fn*2);
  float*  bqkv  = (float*)nxt((size_t)6*Hn*4);
  bf16_t* xn1   = (bf16_t*)nxt((size_t)Tn*Hn*2);
  bf16_t* qkvh  = (bf16_t*)nxt((size_t)6*Bn*NHn*Sn*DHn*2);
  bf16_t* ctxb  = (bf16_t*)nxt((size_t)Ln*Bn*Sn*Hn*2);
  float*  otmp  = (float*)nxt((size_t)Ln*Tn*Hn*4);
  float*  x2    = (float*)nxt((size_t)Tn*Hn*4);
  bf16_t* xn2   = (bf16_t*)nxt((size_t)Tn*Hn*2);
  float*  gates = (float*)nxt((size_t)Tn*2*4);
  int*    lists = (int*)nxt((size_t)En*Tn*4);
  int*    counts= (int*)nxt(256);
  bf16_t* hbuf  = (bf16_t*)nxt((size_t)An*Fn*2);
  bf16_t* ybuf  = (bf16_t*)nxt((size_t)KSPLIT*An*Hn*2);

  hipMemsetAsync(counts, 0, En*sizeof(int), stream);
  hipMemcpyAsync(bqkv,          bq, (size_t)Ln*Hn*4, hipMemcpyDeviceToDevice, stream);
  hipMemcpyAsync(bqkv + 2*Hn,   bk, (size_t)Ln*Hn*4, hipMemcpyDeviceToDevice, stream);
  hipMemcpyAsync(bqkv + 4*Hn,   bv, (size_t)Ln*Hn*4, hipMemcpyDeviceToDevice, stream);

  // weight transpose+convert (64x64 tiles)
  tcvt_k<<<dim3(16,16,Ln), 256, 0, stream>>>(Wq, wqkvT,            Hn, Hn);
  tcvt_k<<<dim3(16,16,Ln), 256, 0, stream>>>(Wk, wqkvT + 2*Hn*Hn,  Hn, Hn);
  tcvt_k<<<dim3(16,16,Ln), 256, 0, stream>>>(Wv, wqkvT + 4*Hn*Hn,  Hn, Hn);
  tcvt_k<<<dim3(16,16,Ln), 256, 0, stream>>>(Wo, woT,              Hn, Hn);
  tcvt_k<<<dim3(Fn/64, Hn/64, En), 256, 0, stream>>>(W1, w1t, Hn, Fn);
  tcvt_k<<<dim3(Hn/64, Fn/64, En), 256, 0, stream>>>(W2, w2t, Fn, Hn);

  ln_k<<<Tn, 256, 0, stream>>>(x, ln1g, ln1b, xn1);

  { GP g{};   // QKV: one dispatch, z = which*2+l in [0,6)
    g.A = xn1; g.Bt = wqkvT; g.bias = bqkv; g.bfout = qkvh;
    g.Kstride = Hn; g.Kloc = Hn;
    gemm_k<0><<<dim3(8,16,6), 256, 0, stream>>>(g); }

  {
    const bf16_t* qh = qkvh;
    const bf16_t* kh = qkvh + (size_t)2*Bn*NHn*Sn*DHn;
    const bf16_t* vt = qkvh + (size_t)4*Bn*NHn*Sn*DHn;
    attn_k<<<dim3(Ln*Bn*NHn, Sn/64), 256, 0, stream>>>(qh, kh, vt, amask, ctxb);
  }

  { GP g{};   // O-proj both levels, z = l
    g.A = ctxb; g.Bt = woT; g.bias = bo; g.fout = otmp;
    g.Kstride = Hn; g.Kloc = Hn;
    gemm_k<1><<<dim3(8,16,2), 256, 0, stream>>>(g); }

  res_ln2_k<<<Tn, 256, 0, stream>>>(x, otmp, otmp + (size_t)Tn*Hn, lvl,
                                    ln2g, ln2b, x2, xn2);
  router_k<<<Tn, 64, 0, stream>>>(x2, ln2g, ln2b, Wr, br, gates, lists, counts);

  { GP g{};   // FFN1: 1D XCD-clustered grid: 16 groups x 256 blocks
    g.A = xn2; g.Bt = w1t; g.bias = b1; g.bfout = hbuf;
    g.list = lists; g.counts = counts;
    g.Kstride = Hn; g.Kloc = Hn;
    gemm_k<3><<<dim3(4096,1,1), 256, 0, stream>>>(g); }
  { GP g{};   // FFN2: 1D XCD-clustered grid: 32 groups x 128 blocks, bf16 partials
    g.A = hbuf; g.Bt = w2t; g.bfout = ybuf; g.bias = b2;
    g.list = lists; g.counts = counts;
    g.Kstride = Fn; g.Kloc = Fn / KSPLIT;
    gemm_k<4><<<dim3(4096,1,1), 256, 0, stream>>>(g); }

  comb_k<<<Tn, 256, 0, stream>>>(x2, ybuf, gates, out);
}